// Round 4
// baseline (274.619 us; speedup 1.0000x reference)
//
#include <hip/hip_runtime.h>

#define E 4096
#define H 32
#define L 8192
#define SCALE 0.08838834764831845f  // 1/sqrt(128)

// workspace layout (float offsets)
#define WS_QACC 0
#define WS_KACC 4096
#define WS_VACC 8192
#define WS_OACC 12288
#define WS_DEN  16384            // 64
#define WS_NUM  16448            // 4096
#define WS_NZ   20544            // 256 uint words (L/32 mask bits)
#define WS_ZERO_FLOATS 20800
#define WS_WBUF 20800            // [L][H] per-slot per-head weights (1 MB, fully overwritten)

typedef float fv4 __attribute__((ext_vector_type(4)));

__device__ __forceinline__ fv4 ntload4(const float* p) {
  return __builtin_nontemporal_load(reinterpret_cast<const fv4*>(p));
}
__device__ __forceinline__ void ntstore4(float* p, fv4 v) {
  __builtin_nontemporal_store(v, reinterpret_cast<fv4*>(p));
}

// ---------------- K0: zero accumulator region -------------------------------
__global__ __launch_bounds__(256) void zero_ws(float* __restrict__ ws) {
  int i = blockIdx.x * 256 + threadIdx.x;
  if (i < WS_ZERO_FLOATS) ws[i] = 0.f;
}

// ---------------- K1: fused q/k/v GEMV (split-K, atomic partials) -----------
__global__ __launch_bounds__(256) void gemv_qkv(const float* __restrict__ x,
    const float* __restrict__ Wq, const float* __restrict__ Wk,
    const float* __restrict__ Wv, float* __restrict__ ws) {
  int b = blockIdx.x;            // 768 blocks: 3 mats x 64 i-chunks x 4 col-groups
  int mat = b >> 8;
  int rem = b & 255;
  int chunk = rem >> 2;          // 64 chunks of 64 rows
  int g = rem & 3;               // 4 col groups of 1024
  const float* W = (mat == 0) ? Wq : (mat == 1) ? Wk : Wv;
  float* acc = ws + ((mat == 0) ? WS_QACC : (mat == 1) ? WS_KACC : WS_VACC);
  int t = threadIdx.x;
  int j = (g << 10) + (t << 2);
  float ax = 0.f, ay = 0.f, az = 0.f, aw = 0.f;
  int i0 = chunk << 6;
  #pragma unroll 8
  for (int r = 0; r < 64; ++r) {
    int i = i0 + r;
    float xi = x[i];
    const fv4 w4 = ntload4(W + (size_t)i * E + j);
    ax += xi * w4.x; ay += xi * w4.y; az += xi * w4.z; aw += xi * w4.w;
  }
  atomicAdd(acc + j + 0, ax);
  atomicAdd(acc + j + 1, ay);
  atomicAdd(acc + j + 2, az);
  atomicAdd(acc + j + 3, aw);
}

// ---------------- K2: fused k+v shift + logits + unconditional accumulation -
// Barrier-free slot loop: numerator needs no mask (w*0 == 0 for zero slots);
// den accumulated unconditionally and fixed up by denfix using wbuf + nz bits.
#define SLOTS 8
__global__ __launch_bounds__(256) void kvpass(const float* __restrict__ kin,
    const float* __restrict__ vin,
    const float* __restrict__ bq, const float* __restrict__ bk,
    const float* __restrict__ bv,
    float* __restrict__ kout, float* __restrict__ vout,
    float* __restrict__ ws) {
  __shared__ float qs[E];
  int t = threadIdx.x;
  const float* qacc = ws + WS_QACC;
  for (int e = t; e < E; e += 256) qs[e] = qacc[e] + bq[e];
  __syncthreads();

  float accx[4] = {0,0,0,0}, accy[4] = {0,0,0,0};
  float accz[4] = {0,0,0,0}, accw[4] = {0,0,0,0};
  float dloc[4] = {0,0,0,0};
  int base = blockIdx.x * SLOTS;
  float* wbuf = ws + WS_WBUF;
  unsigned int* nzm = reinterpret_cast<unsigned int*>(ws + WS_NZ);

  #pragma unroll
  for (int s = 0; s < SLOTS; ++s) {
    int o = base + s;
    fv4 k4[4], v4[4];
    if (o < L - 1) {
      const float* ks = kin + (size_t)(o + 1) * E;
      const float* vs = vin + (size_t)(o + 1) * E;
      #pragma unroll
      for (int c = 0; c < 4; ++c) {
        int e = (c << 10) + (t << 2);
        k4[c] = ntload4(ks + e);
        v4[c] = ntload4(vs + e);
      }
    } else {
      #pragma unroll
      for (int c = 0; c < 4; ++c) {
        int e = (c << 10) + (t << 2);
        const fv4 ka = *reinterpret_cast<const fv4*>(ws + WS_KACC + e);
        const fv4 kb = *reinterpret_cast<const fv4*>(bk + e);
        const fv4 va = *reinterpret_cast<const fv4*>(ws + WS_VACC + e);
        const fv4 vb = *reinterpret_cast<const fv4*>(bv + e);
        k4[c] = ka + kb;
        v4[c] = va + vb;
      }
    }
    float* kd = kout + (size_t)o * E;
    float* vd = vout + (size_t)o * E;
    #pragma unroll
    for (int c = 0; c < 4; ++c) {
      int e = (c << 10) + (t << 2);
      ntstore4(kd + e, k4[c]);
      ntstore4(vd + e, v4[c]);
    }
    bool nz = false;
    #pragma unroll
    for (int c = 0; c < 4; ++c) {
      int e = (c << 10) + (t << 2);
      const fv4 q4 = *reinterpret_cast<const fv4*>(qs + e);
      float pp = k4[c].x * q4.x + k4[c].y * q4.y + k4[c].z * q4.z + k4[c].w * q4.w;
      #pragma unroll
      for (int off = 16; off >= 1; off >>= 1)
        pp += __shfl_xor(pp, off);   // head h = c*8 + (t>>5) dot over 32 lanes
      float w = __expf(pp * SCALE);
      accx[c] += w * v4[c].x; accy[c] += w * v4[c].y;
      accz[c] += w * v4[c].z; accw[c] += w * v4[c].w;
      if ((t & 31) == 0) {
        dloc[c] += w;
        wbuf[(o << 5) + (c << 3) + (t >> 5)] = w;
      }
      nz = nz || v4[c].x != 0.f || v4[c].y != 0.f || v4[c].z != 0.f || v4[c].w != 0.f;
    }
    unsigned long long b = __ballot(nz);
    if ((t & 63) == 0 && b != 0ULL)
      atomicOr(nzm + (o >> 5), 1u << (o & 31));
  }
  float* num = ws + WS_NUM;
  float* den = ws + WS_DEN;
  #pragma unroll
  for (int c = 0; c < 4; ++c) {
    int e = (c << 10) + (t << 2);
    atomicAdd(num + e + 0, accx[c]);
    atomicAdd(num + e + 1, accy[c]);
    atomicAdd(num + e + 2, accz[c]);
    atomicAdd(num + e + 3, accw[c]);
    if ((t & 31) == 0) atomicAdd(den + (c << 3) + (t >> 5), dloc[c]);
  }
}

// ---------------- K3: denominator fixup for all-zero v slots ----------------
__global__ __launch_bounds__(256) void denfix(float* __restrict__ ws) {
  const unsigned int* nzm = reinterpret_cast<const unsigned int*>(ws + WS_NZ);
  int t = threadIdx.x;
  unsigned int m = nzm[t];
  if (m == 0xFFFFFFFFu) return;    // fast path: no masked slots in this word
  const float* wbuf = ws + WS_WBUF;
  for (int b = 0; b < 32; ++b) {
    if (!(m & (1u << b))) {
      int o = (t << 5) + b;
      for (int h = 0; h < H; ++h)
        atomicAdd(ws + WS_DEN + h, -wbuf[(o << 5) + h]);
    }
  }
}

// ---------------- K4: output GEMV (values = num/den on the fly) -------------
__global__ __launch_bounds__(256) void gemv_out(const float* __restrict__ Wo,
    const float* __restrict__ bo, float* __restrict__ ws) {
  int b = blockIdx.x;            // 1024 blocks: 256 i-chunks x 4 col-groups
  int chunk = b >> 2;            // 16 rows each
  int g = b & 3;
  int t = threadIdx.x;
  int j = (g << 10) + (t << 2);
  const float* num = ws + WS_NUM;
  const float* den = ws + WS_DEN;
  __shared__ float vals[16];
  int i0 = chunk << 4;
  if (t < 16) vals[t] = num[i0 + t] / den[(i0 + t) >> 7];
  __syncthreads();
  float ax = 0.f, ay = 0.f, az = 0.f, aw = 0.f;
  #pragma unroll
  for (int r = 0; r < 16; ++r) {
    int i = i0 + r;
    float vi = vals[r];
    const fv4 w4 = ntload4(Wo + (size_t)i * E + j);
    ax += vi * w4.x; ay += vi * w4.y; az += vi * w4.z; aw += vi * w4.w;
  }
  if (chunk == 0) {
    const fv4 b4 = *reinterpret_cast<const fv4*>(bo + j);
    ax += b4.x; ay += b4.y; az += b4.z; aw += b4.w;
  }
  float* oacc = ws + WS_OACC;
  atomicAdd(oacc + j + 0, ax);
  atomicAdd(oacc + j + 1, ay);
  atomicAdd(oacc + j + 2, az);
  atomicAdd(oacc + j + 3, aw);
}

// ---------------- K5: final store of out_i ----------------------------------
__global__ __launch_bounds__(256) void writeout(const float* __restrict__ ws,
                                                float* __restrict__ out) {
  int i = blockIdx.x * 256 + threadIdx.x;
  out[i] = ws[WS_OACC + i];
}

extern "C" void kernel_launch(void* const* d_in, const int* in_sizes, int n_in,
                              void* d_out, int out_size, void* d_ws, size_t ws_size,
                              hipStream_t stream) {
  const float* x   = (const float*)d_in[0];
  const float* vin = (const float*)d_in[1];
  const float* kin = (const float*)d_in[2];
  const float* Wv  = (const float*)d_in[3];
  const float* bv  = (const float*)d_in[4];
  const float* Wq  = (const float*)d_in[5];
  const float* bq  = (const float*)d_in[6];
  const float* Wk  = (const float*)d_in[7];
  const float* bk  = (const float*)d_in[8];
  const float* Wo  = (const float*)d_in[9];
  const float* bo  = (const float*)d_in[10];
  float* out  = (float*)d_out;
  float* vout = out + E;
  float* kout = vout + (size_t)L * E;
  float* ws   = (float*)d_ws;

  zero_ws<<<(WS_ZERO_FLOATS + 255) / 256, 256, 0, stream>>>(ws);
  gemv_qkv<<<768, 256, 0, stream>>>(x, Wq, Wk, Wv, ws);
  kvpass<<<L / SLOTS, 256, 0, stream>>>(kin, vin, bq, bk, bv, kout, vout, ws);
  denfix<<<1, 256, 0, stream>>>(ws);
  gemv_out<<<1024, 256, 0, stream>>>(Wo, bo, ws);
  writeout<<<16, 256, 0, stream>>>(ws, out);
}